// Round 2
// baseline (168.363 us; speedup 1.0000x reference)
//
#include <hip/hip_runtime.h>
#include <cstddef>

typedef short short8 __attribute__((ext_vector_type(8)));
typedef unsigned short ushort8 __attribute__((ext_vector_type(8)));
typedef float f32x4 __attribute__((ext_vector_type(4)));

#define AS1(p) ((const __attribute__((address_space(1))) void*)(p))
#define AS3(p) ((__attribute__((address_space(3))) void*)(p))

__device__ __forceinline__ unsigned short f2bf(float f) {
  unsigned int u = __builtin_bit_cast(unsigned int, f);
  u += 0x7FFFu + ((u >> 16) & 1u);   // round-to-nearest-even
  return (unsigned short)(u >> 16);
}

__device__ __forceinline__ void gload_lds16(const void* g, void* l) {
  __builtin_amdgcn_global_load_lds(AS1(g), AS3(l), 16, 0, 0);
}

// ---------------------------------------------------------------------------
// fp32 -> bf16 elementwise convert (float4 in, 4x bf16 out)
// ---------------------------------------------------------------------------
__global__ void cvt_f32_bf16(const float* __restrict__ in,
                             unsigned short* __restrict__ out, int n4) {
  int i = blockIdx.x * blockDim.x + threadIdx.x;
  if (i >= n4) return;
  float4 v = *reinterpret_cast<const float4*>(in + (size_t)i * 4);
  ushort4 o;
  o.x = f2bf(v.x); o.y = f2bf(v.y); o.z = f2bf(v.z); o.w = f2bf(v.w);
  *reinterpret_cast<ushort4*>(out + (size_t)i * 4) = o;
}

// ---------------------------------------------------------------------------
// fp32 [Kd][Nd] -> bf16 [Nd][Kd] tiled transpose+convert, block (32,8)
// ---------------------------------------------------------------------------
__global__ void transpose_cvt(const float* __restrict__ in,
                              unsigned short* __restrict__ out,
                              int Kd, int Nd) {
  __shared__ float tile[32][33];
  const int n0 = blockIdx.x * 32;
  const int k0 = blockIdx.y * 32;
  const int tx = threadIdx.x;
  const int ty = threadIdx.y;
#pragma unroll
  for (int i = 0; i < 4; ++i)
    tile[ty + i * 8][tx] = in[(size_t)(k0 + ty + i * 8) * Nd + n0 + tx];
  __syncthreads();
#pragma unroll
  for (int i = 0; i < 4; ++i)
    out[(size_t)(n0 + ty + i * 8) * Kd + k0 + tx] = f2bf(tile[tx][ty + i * 8]);
}

// ---------------------------------------------------------------------------
// GEMM: C[M][N] = A[M][K] * B'[N][K] (+bias or +C_old, optional relu+bf16 out)
// 128x128 tile, BK=64, 4 waves (2x2), 16x16x32 MFMA.
// A_F32=1: A is f32, reg-staged + converted + swizzled ds_write (rule #21 both-
// sides). A_F32=0: A is bf16, global_load_lds w/ pre-swizzled source.
// LDS involution: addr ^= ((addr>>7)&7)<<4.
// ---------------------------------------------------------------------------
template <int A_F32, int RELU_BF16_OUT>
__global__ __launch_bounds__(256, 2)
void gemm_bf16(const void* __restrict__ Ap, int lda,          // elements
               const unsigned short* __restrict__ B, int ldb, // [*][ldb] bf16
               const float* __restrict__ bias,
               void* __restrict__ C, int ldc,
               int K, int beta) {
  __shared__ char lds[32768];
  char* const As = lds;
  char* const Bs = lds + 16384;

  const int tid  = threadIdx.x;
  const int lane = tid & 63;
  const int w    = tid >> 6;
  const int wm   = w >> 1;
  const int wn   = w & 1;
  const int m0   = blockIdx.y * 128;
  const int n0   = blockIdx.x * 128;

  f32x4 acc[4][4];
#pragma unroll
  for (int i = 0; i < 4; ++i)
#pragma unroll
    for (int j = 0; j < 4; ++j)
      acc[i][j] = (f32x4){0.f, 0.f, 0.f, 0.f};

  // gload_lds staging map: linear LDS dest, pre-swizzled global source.
  int srow[4], scol[4], sbase[4];
#pragma unroll
  for (int j = 0; j < 4; ++j) {
    const int stored  = (j * 256 + tid) * 16;
    const int natural = stored ^ (((stored >> 7) & 7) << 4);
    srow[j]  = natural >> 7;          // logical tile row (0..127)
    scol[j]  = (natural & 127) >> 1;  // logical k element (multiple of 8)
    sbase[j] = (j * 256 + (tid & 192)) * 16;  // wave-uniform LDS base
  }

  // A_F32 reg-staging map: thread handles 4 groups of 8 f32 -> 8 bf16.
  size_t agofs[4];
  int ast[4];
  if (A_F32) {
#pragma unroll
    for (int p = 0; p < 4; ++p) {
      const int idx = p * 256 + tid;      // 0..1023
      const int r   = idx >> 3;           // tile row 0..127
      const int kbe = (idx & 7) * 8;      // k element 0,8,..,56
      agofs[p] = (size_t)(m0 + r) * lda + kbe;
      const int nat = r * 128 + kbe * 2;  // logical byte addr
      ast[p] = nat ^ (((nat >> 7) & 7) << 4);
    }
  }

  const int nsteps = K >> 6;
  for (int ks = 0; ks < nsteps; ++ks) {
    const int k0 = ks << 6;
    if (A_F32) {
      const float* Af = (const float*)Ap;
#pragma unroll
      for (int p = 0; p < 4; ++p) {
        const float* s = Af + agofs[p] + k0;
        float4 x0 = *reinterpret_cast<const float4*>(s);
        float4 x1 = *reinterpret_cast<const float4*>(s + 4);
        ushort8 v;
        v[0] = f2bf(x0.x); v[1] = f2bf(x0.y); v[2] = f2bf(x0.z); v[3] = f2bf(x0.w);
        v[4] = f2bf(x1.x); v[5] = f2bf(x1.y); v[6] = f2bf(x1.z); v[7] = f2bf(x1.w);
        *reinterpret_cast<ushort8*>(As + ast[p]) = v;  // swizzled write
      }
    } else {
      const unsigned short* Ab = (const unsigned short*)Ap;
#pragma unroll
      for (int j = 0; j < 4; ++j)
        gload_lds16(Ab + (size_t)(m0 + srow[j]) * lda + (k0 + scol[j]),
                    As + sbase[j]);
    }
#pragma unroll
    for (int j = 0; j < 4; ++j)
      gload_lds16(B + (size_t)(n0 + srow[j]) * ldb + (k0 + scol[j]),
                  Bs + sbase[j]);
    __syncthreads();   // drains vmcnt (gload_lds) + lgkmcnt (ds_write)

#pragma unroll
    for (int kk = 0; kk < 2; ++kk) {
      const int kb = kk * 64 + (lane >> 4) * 16;   // byte offset in row
      short8 af[4], bfv[4];
#pragma unroll
      for (int mi = 0; mi < 4; ++mi) {
        int nat = (wm * 64 + mi * 16 + (lane & 15)) * 128 + kb;
        int st  = nat ^ (((nat >> 7) & 7) << 4);
        af[mi] = *reinterpret_cast<const short8*>(As + st);
      }
#pragma unroll
      for (int ni = 0; ni < 4; ++ni) {
        int nat = (wn * 64 + ni * 16 + (lane & 15)) * 128 + kb;
        int st  = nat ^ (((nat >> 7) & 7) << 4);
        bfv[ni] = *reinterpret_cast<const short8*>(Bs + st);
      }
#pragma unroll
      for (int mi = 0; mi < 4; ++mi)
#pragma unroll
        for (int ni = 0; ni < 4; ++ni)
          acc[mi][ni] = __builtin_amdgcn_mfma_f32_16x16x32_bf16(
              af[mi], bfv[ni], acc[mi][ni], 0, 0, 0);
    }
    __syncthreads();   // all reads done before next stage overwrites
  }

  // Epilogue: D row = (lane>>4)*4 + reg, col = lane&15 (m89-verified)
  const int row0 = m0 + wm * 64 + (lane >> 4) * 4;
  const int col0 = n0 + wn * 64 + (lane & 15);
#pragma unroll
  for (int ni = 0; ni < 4; ++ni) {
    const int c = col0 + ni * 16;
    const float bv = beta ? 0.f : bias[c];
#pragma unroll
    for (int mi = 0; mi < 4; ++mi) {
#pragma unroll
      for (int r = 0; r < 4; ++r) {
        const size_t idx = (size_t)(row0 + mi * 16 + r) * ldc + c;
        float v = acc[mi][ni][r] + bv;
        if (RELU_BF16_OUT) {
          v = v > 0.f ? v : 0.f;
          ((unsigned short*)C)[idx] = f2bf(v);
        } else {
          if (beta) v += ((float*)C)[idx];
          ((float*)C)[idx] = v;
        }
      }
    }
  }
}

// ---------------------------------------------------------------------------
extern "C" void kernel_launch(void* const* d_in, const int* in_sizes, int n_in,
                              void* d_out, int out_size, void* d_ws, size_t ws_size,
                              hipStream_t stream) {
  const float* X  = (const float*)d_in[0];  // [8192][1024]
  const float* W1 = (const float*)d_in[1];  // [1024][4096]
  const float* b1 = (const float*)d_in[2];  // [4096]
  const float* W2 = (const float*)d_in[3];  // [4096][1024]
  const float* b2 = (const float*)d_in[4];  // [1024]
  float* out = (float*)d_out;               // [8192][1024] f32

  const int M = 8192, H = 1024, I = 4096;
  const size_t MB = 1024 * 1024;

  // ws layout: [0,8MB) W1t [I][H], [8,16MB) W2t [H][I], rest per config.
  char* ws = (char*)d_ws;
  unsigned short* W1t = (unsigned short*)ws;
  unsigned short* W2t = (unsigned short*)(ws + 8 * MB);

  // Adaptive config: never touch memory beyond ws_size (round-1 postmortem:
  // overflow corrupted un-restored inputs -> post-timing divergence).
  int Ic;            // I-chunk width (K of layer-2 partial); RMW out across chunks
  int useXbf;        // pre-convert X to bf16?
  unsigned short* Xbf = nullptr;
  unsigned short* Hc;
  if (ws_size >= 80 * MB) {
    // Unchunked. Xbf lives in d_out tail: fully consumed by L1 before the
    // single L2 writes out (stream-serialized).
    Ic = 4096; useXbf = 1;
    Xbf = (unsigned short*)((char*)d_out + 16 * MB);
    Hc  = (unsigned short*)(ws + 16 * MB);            // 64 MB
  } else if (ws_size >= 64 * MB) {
    Ic = 2048; useXbf = 1;
    Xbf = (unsigned short*)(ws + 16 * MB);            // 16 MB
    Hc  = (unsigned short*)(ws + 32 * MB);            // 32 MB
  } else if (ws_size >= 48 * MB) {
    Ic = 1024; useXbf = 1;
    Xbf = (unsigned short*)(ws + 16 * MB);
    Hc  = (unsigned short*)(ws + 32 * MB);            // 16 MB
  } else if (ws_size >= 32 * MB) {
    Ic = 1024; useXbf = 0;
    Hc  = (unsigned short*)(ws + 16 * MB);            // 16 MB
  } else if (ws_size >= 24 * MB) {
    Ic = 512;  useXbf = 0;
    Hc  = (unsigned short*)(ws + 16 * MB);
  } else if (ws_size >= 20 * MB) {
    Ic = 256;  useXbf = 0;
    Hc  = (unsigned short*)(ws + 16 * MB);
  } else {
    Ic = 128;  useXbf = 0;
    Hc  = (unsigned short*)(ws + 16 * MB);
  }

  transpose_cvt<<<dim3(I / 32, H / 32), dim3(32, 8), 0, stream>>>(W1, W1t, H, I);
  transpose_cvt<<<dim3(H / 32, I / 32), dim3(32, 8), 0, stream>>>(W2, W2t, I, H);
  if (useXbf) {
    int n4 = (M * H) / 4;
    cvt_f32_bf16<<<(n4 + 255) / 256, 256, 0, stream>>>(X, Xbf, n4);
  }

  const int nch = I / Ic;
  for (int c = 0; c < nch; ++c) {
    const int i0 = c * Ic;
    // layer-1 partial: Hc[M][Ic] = relu(X * W1[:, i0:i0+Ic] + b1[i0:])
    if (useXbf)
      gemm_bf16<0, 1><<<dim3(Ic / 128, M / 128), 256, 0, stream>>>(
          Xbf, H, W1t + (size_t)i0 * H, H, b1 + i0, Hc, Ic, H, 0);
    else
      gemm_bf16<1, 1><<<dim3(Ic / 128, M / 128), 256, 0, stream>>>(
          X, H, W1t + (size_t)i0 * H, H, b1 + i0, Hc, Ic, H, 0);
    // layer-2 partial: out (+)= Hc * W2[i0:i0+Ic, :] (+ b2 on first chunk)
    gemm_bf16<0, 0><<<dim3(H / 128, M / 128), 256, 0, stream>>>(
        Hc, Ic, W2t + i0, I, b2, out, H, Ic, c > 0);
  }
}

// Round 3
// 165.445 us; speedup vs baseline: 1.0176x; 1.0176x over previous
//
#include <hip/hip_runtime.h>
#include <cstddef>

typedef short short8 __attribute__((ext_vector_type(8)));
typedef unsigned short ushort8 __attribute__((ext_vector_type(8)));
typedef float f32x4 __attribute__((ext_vector_type(4)));

#define AS1(p) ((const __attribute__((address_space(1))) void*)(p))
#define AS3(p) ((__attribute__((address_space(3))) void*)(p))

__device__ __forceinline__ unsigned short f2bf(float f) {
  unsigned int u = __builtin_bit_cast(unsigned int, f);
  u += 0x7FFFu + ((u >> 16) & 1u);   // round-to-nearest-even
  return (unsigned short)(u >> 16);
}

__device__ __forceinline__ void gload_lds16(const void* g, void* l) {
  __builtin_amdgcn_global_load_lds(AS1(g), AS3(l), 16, 0, 0);
}

// ---------------------------------------------------------------------------
// fp32 -> bf16 elementwise convert (float4 in, 4x bf16 out)
// ---------------------------------------------------------------------------
__global__ void cvt_f32_bf16(const float* __restrict__ in,
                             unsigned short* __restrict__ out, int n4) {
  int i = blockIdx.x * blockDim.x + threadIdx.x;
  if (i >= n4) return;
  float4 v = *reinterpret_cast<const float4*>(in + (size_t)i * 4);
  ushort4 o;
  o.x = f2bf(v.x); o.y = f2bf(v.y); o.z = f2bf(v.z); o.w = f2bf(v.w);
  *reinterpret_cast<ushort4*>(out + (size_t)i * 4) = o;
}

// ---------------------------------------------------------------------------
// fp32 [Kd][Nd] -> bf16 [Nd][Kd] tiled transpose+convert, block (32,8)
// ---------------------------------------------------------------------------
__global__ void transpose_cvt(const float* __restrict__ in,
                              unsigned short* __restrict__ out,
                              int Kd, int Nd) {
  __shared__ float tile[32][33];
  const int n0 = blockIdx.x * 32;
  const int k0 = blockIdx.y * 32;
  const int tx = threadIdx.x;
  const int ty = threadIdx.y;
#pragma unroll
  for (int i = 0; i < 4; ++i)
    tile[ty + i * 8][tx] = in[(size_t)(k0 + ty + i * 8) * Nd + n0 + tx];
  __syncthreads();
#pragma unroll
  for (int i = 0; i < 4; ++i)
    out[(size_t)(n0 + ty + i * 8) * Kd + k0 + tx] = f2bf(tile[tx][ty + i * 8]);
}

// ---------------------------------------------------------------------------
// 8-phase 256-row GEMM (T2+T3+T4+T5 port): C[M][BN*nbx] = A[M][K]*B'[N][K]
// BM=256, BK=64, 8 waves (2M x 4N), 512 thr, double-buffered LDS,
// counted vmcnt (never 0 mid-loop), setprio around MFMA cluster,
// LDS involution a^=((a>>7)&7)<<4 on stage-source + ds_read (both sides).
// Stage stream (forced by last-read analysis):
//   P1:B1(t+1) P2:A0(t+1) P3:A1(t+1) P4:B0(t+2) P5:B1(t+2) P6:A0(t+2)
//   P7:A1(t+2) P8:B0(t+3);  waits at P4/P8 only, allowance = LOADS_B.
// ---------------------------------------------------------------------------
#define PH(ABUF, BBUF, H, KK, STAGE, WAITC)                                    \
  {                                                                            \
    if ((H) == 0) {                                                            \
      _Pragma("unroll")                                                        \
      for (int ni = 0; ni < NB; ++ni)                                          \
        bfr[ni] = *reinterpret_cast<const short8*>((BBUF) + bread[ni][KK]);    \
    }                                                                          \
    short8 afr[4];                                                             \
    _Pragma("unroll")                                                          \
    for (int m2 = 0; m2 < 4; ++m2)                                             \
      afr[m2] = *reinterpret_cast<const short8*>((ABUF) + aread[(H)*4+m2][KK]);\
    STAGE;                                                                     \
    __builtin_amdgcn_s_barrier();                                              \
    asm volatile("s_waitcnt lgkmcnt(0)" ::: "memory");                         \
    __builtin_amdgcn_sched_barrier(0);                                         \
    __builtin_amdgcn_s_setprio(1);                                             \
    _Pragma("unroll")                                                          \
    for (int m2 = 0; m2 < 4; ++m2) {                                           \
      _Pragma("unroll")                                                        \
      for (int ni = 0; ni < NB; ++ni)                                          \
        acc[(H)*4+m2][ni] = __builtin_amdgcn_mfma_f32_16x16x32_bf16(           \
            afr[m2], bfr[ni], acc[(H)*4+m2][ni], 0, 0, 0);                     \
    }                                                                          \
    __builtin_amdgcn_s_setprio(0);                                             \
    WAITC;                                                                     \
    __builtin_amdgcn_s_barrier();                                              \
  }

template <int BN, int RELU_BF16_OUT>
__global__ __launch_bounds__(512, 2)
void gemm8p(const unsigned short* __restrict__ A, int lda,
            const unsigned short* __restrict__ Bp, int ldb,
            const float* __restrict__ bias,
            void* __restrict__ C, int ldc, int K, int nbx) {
  constexpr int PWN     = BN / 4;        // per-wave N (64 or 32)
  constexpr int NB      = PWN / 16;      // B frags per wave (4 or 2)
  constexpr int LOADS_B = BN / 128;      // gload_lds per B-half (2 or 1)
  constexpr int BHROWS  = BN / 2;        // rows per B-half
  constexpr int BHSZ    = BHROWS * 128;  // bytes per B-half (64el*2B rows)
  extern __shared__ char lds[];
  char* const A0b = lds;
  char* const A1b = lds + 32768;
  char* const B0b = lds + 65536;
  char* const B1b = lds + 65536 + 2 * BHSZ;

  const int tid  = threadIdx.x;
  const int lane = tid & 63;
  const int wid  = tid >> 6;
  const int wm   = wid >> 2;   // 0..1
  const int wn   = wid & 3;    // 0..3

  // XCD-chunked swizzle: each XCD gets a contiguous logical chunk.
  const int cpx     = gridDim.x >> 3;
  const int logical = (blockIdx.x & 7) * cpx + (blockIdx.x >> 3);
  const int bx = logical % nbx;
  const int by = logical / nbx;
  const int m0 = by * 256;
  const int n0 = bx * BN;

  f32x4 acc[8][NB];
#pragma unroll
  for (int i = 0; i < 8; ++i)
#pragma unroll
    for (int j = 0; j < NB; ++j)
      acc[i][j] = (f32x4){0.f, 0.f, 0.f, 0.f};

  // --- stage maps: linear LDS dest, pre-swizzled global source -------------
  size_t aofs0, aofs1, bofs0, bofs1 = 0;
  {
    int sr = tid * 16, nat = sr ^ (((sr >> 7) & 7) << 4);
    aofs0 = (size_t)(m0 + (nat >> 7)) * lda + ((nat & 127) >> 1);
    bofs0 = (size_t)(n0 + (nat >> 7)) * ldb + ((nat & 127) >> 1);
    sr = (512 + tid) * 16; nat = sr ^ (((sr >> 7) & 7) << 4);
    aofs1 = (size_t)(m0 + (nat >> 7)) * lda + ((nat & 127) >> 1);
    if (LOADS_B == 2)
      bofs1 = (size_t)(n0 + (nat >> 7)) * ldb + ((nat & 127) >> 1);
  }
  const int dst0 = (tid & 448) * 16;        // wave-uniform base, lane*16 added by HW
  const int dst1 = dst0 + 8192;

  auto stA = [&](char* ab, int half, int kel) {
    gload_lds16(A + aofs0 + (size_t)half * 128 * lda + kel, ab + half * 16384 + dst0);
    gload_lds16(A + aofs1 + (size_t)half * 128 * lda + kel, ab + half * 16384 + dst1);
  };
  auto stB = [&](char* bb, int half, int kel) {
    gload_lds16(Bp + bofs0 + (size_t)half * BHROWS * ldb + kel, bb + half * BHSZ + dst0);
    if constexpr (LOADS_B == 2)
      gload_lds16(Bp + bofs1 + (size_t)half * BHROWS * ldb + kel, bb + half * BHSZ + dst1);
  };
  auto waitLB = [&]() {
    if constexpr (LOADS_B == 2) asm volatile("s_waitcnt vmcnt(2)" ::: "memory");
    else                        asm volatile("s_waitcnt vmcnt(1)" ::: "memory");
  };

  // --- fragment-read swizzled offsets --------------------------------------
  int aread[8][2], bread[NB][2];
#pragma unroll
  for (int mi = 0; mi < 8; ++mi)
#pragma unroll
    for (int kk = 0; kk < 2; ++kk) {
      int nat = (wm * 128 + mi * 16 + (lane & 15)) * 128 + kk * 64 + (lane >> 4) * 16;
      aread[mi][kk] = nat ^ (((nat >> 7) & 7) << 4);
    }
#pragma unroll
  for (int ni = 0; ni < NB; ++ni)
#pragma unroll
    for (int kk = 0; kk < 2; ++kk) {
      int nat = (wn * PWN + ni * 16 + (lane & 15)) * 128 + kk * 64 + (lane >> 4) * 16;
      bread[ni][kk] = nat ^ (((nat >> 7) & 7) << 4);
    }

  // --- prologue: tile0 (buf0) + B0(tile1); wait tile0 complete -------------
  stB(B0b, 0, 0);
  stB(B0b, 1, 0);
  stA(A0b, 0, 0);
  stA(A0b, 1, 0);
  stB(B1b, 0, 64);
  waitLB();
  __builtin_amdgcn_s_barrier();

  const int niter = K >> 7;   // 2 K-tiles (BK=64) per iteration
  for (int it = 0; it < niter; ++it) {
    const bool last = (it == niter - 1);
    const int kb = it << 7;
    short8 bfr[NB];
    PH(A0b, B0b, 0, 0, stB(B1b, 1, kb + 64), ((void)0));
    PH(A0b, B0b, 1, 0, stA(A1b, 0, kb + 64), ((void)0));
    PH(A0b, B0b, 0, 1, stA(A1b, 1, kb + 64), ((void)0));
    PH(A0b, B0b, 1, 1, { if (!last) stB(B0b, 0, kb + 128); },
       { if (last) { asm volatile("s_waitcnt vmcnt(0)" ::: "memory"); } else waitLB(); });
    PH(A1b, B1b, 0, 0, { if (!last) stB(B0b, 1, kb + 128); }, ((void)0));
    PH(A1b, B1b, 1, 0, { if (!last) stA(A0b, 0, kb + 128); }, ((void)0));
    PH(A1b, B1b, 0, 1, { if (!last) stA(A0b, 1, kb + 128); }, ((void)0));
    PH(A1b, B1b, 1, 1, { if (!last) stB(B1b, 0, kb + 192); },
       { if (!last) waitLB(); });
  }

  // --- epilogue: D row=(lane>>4)*4+reg, col=lane&15 (m89-verified) ---------
  const int row0 = m0 + wm * 128 + (lane >> 4) * 4;
  const int col0 = n0 + wn * PWN + (lane & 15);
#pragma unroll
  for (int ni = 0; ni < NB; ++ni) {
    const int c = col0 + ni * 16;
    const float bv = bias[c];
#pragma unroll
    for (int mi = 0; mi < 8; ++mi) {
#pragma unroll
      for (int r = 0; r < 4; ++r) {
        const size_t idx = (size_t)(row0 + mi * 16 + r) * ldc + c;
        float v = acc[mi][ni][r] + bv;
        if (RELU_BF16_OUT) {
          v = v > 0.f ? v : 0.f;
          ((unsigned short*)C)[idx] = f2bf(v);
        } else {
          ((float*)C)[idx] = v;
        }
      }
    }
  }
}

// ---------------------------------------------------------------------------
// Fallback 128^2 GEMM (round-2, verified) for small-ws configurations.
// ---------------------------------------------------------------------------
template <int A_F32, int RELU_BF16_OUT>
__global__ __launch_bounds__(256, 2)
void gemm_bf16(const void* __restrict__ Ap, int lda,
               const unsigned short* __restrict__ B, int ldb,
               const float* __restrict__ bias,
               void* __restrict__ C, int ldc,
               int K, int beta) {
  __shared__ char lds[32768];
  char* const As = lds;
  char* const Bs = lds + 16384;

  const int tid  = threadIdx.x;
  const int lane = tid & 63;
  const int w    = tid >> 6;
  const int wm   = w >> 1;
  const int wn   = w & 1;
  const int m0   = blockIdx.y * 128;
  const int n0   = blockIdx.x * 128;

  f32x4 acc[4][4];
#pragma unroll
  for (int i = 0; i < 4; ++i)
#pragma unroll
    for (int j = 0; j < 4; ++j)
      acc[i][j] = (f32x4){0.f, 0.f, 0.f, 0.f};

  int srow[4], scol[4], sbase[4];
#pragma unroll
  for (int j = 0; j < 4; ++j) {
    const int stored  = (j * 256 + tid) * 16;
    const int natural = stored ^ (((stored >> 7) & 7) << 4);
    srow[j]  = natural >> 7;
    scol[j]  = (natural & 127) >> 1;
    sbase[j] = (j * 256 + (tid & 192)) * 16;
  }

  size_t agofs[4];
  int ast[4];
  if (A_F32) {
#pragma unroll
    for (int p = 0; p < 4; ++p) {
      const int idx = p * 256 + tid;
      const int r   = idx >> 3;
      const int kbe = (idx & 7) * 8;
      agofs[p] = (size_t)(m0 + r) * lda + kbe;
      const int nat = r * 128 + kbe * 2;
      ast[p] = nat ^ (((nat >> 7) & 7) << 4);
    }
  }

  const int nsteps = K >> 6;
  for (int ks = 0; ks < nsteps; ++ks) {
    const int k0 = ks << 6;
    if (A_F32) {
      const float* Af = (const float*)Ap;
#pragma unroll
      for (int p = 0; p < 4; ++p) {
        const float* s = Af + agofs[p] + k0;
        float4 x0 = *reinterpret_cast<const float4*>(s);
        float4 x1 = *reinterpret_cast<const float4*>(s + 4);
        ushort8 v;
        v[0] = f2bf(x0.x); v[1] = f2bf(x0.y); v[2] = f2bf(x0.z); v[3] = f2bf(x0.w);
        v[4] = f2bf(x1.x); v[5] = f2bf(x1.y); v[6] = f2bf(x1.z); v[7] = f2bf(x1.w);
        *reinterpret_cast<ushort8*>(As + ast[p]) = v;
      }
    } else {
      const unsigned short* Ab = (const unsigned short*)Ap;
#pragma unroll
      for (int j = 0; j < 4; ++j)
        gload_lds16(Ab + (size_t)(m0 + srow[j]) * lda + (k0 + scol[j]),
                    As + sbase[j]);
    }
#pragma unroll
    for (int j = 0; j < 4; ++j)
      gload_lds16(B + (size_t)(n0 + srow[j]) * ldb + (k0 + scol[j]),
                  Bs + sbase[j]);
    __syncthreads();

#pragma unroll
    for (int kk = 0; kk < 2; ++kk) {
      const int kb = kk * 64 + (lane >> 4) * 16;
      short8 af[4], bfv[4];
#pragma unroll
      for (int mi = 0; mi < 4; ++mi) {
        int nat = (wm * 64 + mi * 16 + (lane & 15)) * 128 + kb;
        int st  = nat ^ (((nat >> 7) & 7) << 4);
        af[mi] = *reinterpret_cast<const short8*>(As + st);
      }
#pragma unroll
      for (int ni = 0; ni < 4; ++ni) {
        int nat = (wn * 64 + ni * 16 + (lane & 15)) * 128 + kb;
        int st  = nat ^ (((nat >> 7) & 7) << 4);
        bfv[ni] = *reinterpret_cast<const short8*>(Bs + st);
      }
#pragma unroll
      for (int mi = 0; mi < 4; ++mi)
#pragma unroll
        for (int ni = 0; ni < 4; ++ni)
          acc[mi][ni] = __builtin_amdgcn_mfma_f32_16x16x32_bf16(
              af[mi], bfv[ni], acc[mi][ni], 0, 0, 0);
    }
    __syncthreads();
  }

  const int row0 = m0 + wm * 64 + (lane >> 4) * 4;
  const int col0 = n0 + wn * 64 + (lane & 15);
#pragma unroll
  for (int ni = 0; ni < 4; ++ni) {
    const int c = col0 + ni * 16;
    const float bv = beta ? 0.f : bias[c];
#pragma unroll
    for (int mi = 0; mi < 4; ++mi) {
#pragma unroll
      for (int r = 0; r < 4; ++r) {
        const size_t idx = (size_t)(row0 + mi * 16 + r) * ldc + c;
        float v = acc[mi][ni][r] + bv;
        if (RELU_BF16_OUT) {
          v = v > 0.f ? v : 0.f;
          ((unsigned short*)C)[idx] = f2bf(v);
        } else {
          if (beta) v += ((float*)C)[idx];
          ((float*)C)[idx] = v;
        }
      }
    }
  }
}

// ---------------------------------------------------------------------------
extern "C" void kernel_launch(void* const* d_in, const int* in_sizes, int n_in,
                              void* d_out, int out_size, void* d_ws, size_t ws_size,
                              hipStream_t stream) {
  const float* X  = (const float*)d_in[0];  // [8192][1024]
  const float* W1 = (const float*)d_in[1];  // [1024][4096]
  const float* b1 = (const float*)d_in[2];  // [4096]
  const float* W2 = (const float*)d_in[3];  // [4096][1024]
  const float* b2 = (const float*)d_in[4];  // [1024]
  float* out = (float*)d_out;               // [8192][1024] f32

  const int M = 8192, H = 1024, I = 4096;
  const size_t MB = 1024 * 1024;

  char* ws = (char*)d_ws;
  unsigned short* W1t = (unsigned short*)ws;            // [I][H] bf16, 8 MB
  unsigned short* W2t = (unsigned short*)(ws + 8 * MB); // [H][I] bf16, 8 MB

  transpose_cvt<<<dim3(I / 32, H / 32), dim3(32, 8), 0, stream>>>(W1, W1t, H, I);
  transpose_cvt<<<dim3(H / 32, I / 32), dim3(32, 8), 0, stream>>>(W2, W2t, I, H);

  if (ws_size >= 80 * MB) {
    // Fast path: 8-phase 256-row GEMMs. Xbf in d_out tail (consumed by L1
    // before the single L2 dispatch overwrites d_out; stream-serialized).
    unsigned short* Xbf = (unsigned short*)((char*)d_out + 16 * MB);
    unsigned short* Hbf = (unsigned short*)(ws + 16 * MB);   // [M][I] bf16, 64 MB
    int n4 = (M * H) / 4;
    cvt_f32_bf16<<<(n4 + 255) / 256, 256, 0, stream>>>(X, Xbf, n4);
    // L1: Hbf = relu(X*W1+b1). grid 16x32=512 blocks (2/CU), 128 KiB LDS.
    gemm8p<256, 1><<<512, 512, 131072, stream>>>(Xbf, H, W1t, H, b1, Hbf, I, H, I / 256);
    // L2: out = Hbf*W2+b2. BN=128: grid 8x32=256 blocks (1/CU), 96 KiB LDS.
    gemm8p<128, 0><<<256, 512, 98304, stream>>>(Hbf, I, W2t, I, b2, out, H, I, H / 128);
    return;
  }

  // Fallback: round-2 adaptive chunked path (verified).
  int Ic, useXbf;
  unsigned short* Xbf = nullptr;
  unsigned short* Hc;
  if (ws_size >= 64 * MB) {
    Ic = 2048; useXbf = 1;
    Xbf = (unsigned short*)(ws + 16 * MB);
    Hc  = (unsigned short*)(ws + 32 * MB);
  } else if (ws_size >= 48 * MB) {
    Ic = 1024; useXbf = 1;
    Xbf = (unsigned short*)(ws + 16 * MB);
    Hc  = (unsigned short*)(ws + 32 * MB);
  } else if (ws_size >= 32 * MB) {
    Ic = 1024; useXbf = 0;
    Hc  = (unsigned short*)(ws + 16 * MB);
  } else if (ws_size >= 24 * MB) {
    Ic = 512;  useXbf = 0;
    Hc  = (unsigned short*)(ws + 16 * MB);
  } else if (ws_size >= 20 * MB) {
    Ic = 256;  useXbf = 0;
    Hc  = (unsigned short*)(ws + 16 * MB);
  } else {
    Ic = 128;  useXbf = 0;
    Hc  = (unsigned short*)(ws + 16 * MB);
  }

  if (useXbf) {
    int n4 = (M * H) / 4;
    cvt_f32_bf16<<<(n4 + 255) / 256, 256, 0, stream>>>(X, Xbf, n4);
  }

  const int nch = I / Ic;
  for (int c = 0; c < nch; ++c) {
    const int i0 = c * Ic;
    if (useXbf)
      gemm_bf16<0, 1><<<dim3(Ic / 128, M / 128), 256, 0, stream>>>(
          Xbf, H, W1t + (size_t)i0 * H, H, b1 + i0, Hc, Ic, H, 0);
    else
      gemm_bf16<1, 1><<<dim3(Ic / 128, M / 128), 256, 0, stream>>>(
          X, H, W1t + (size_t)i0 * H, H, b1 + i0, Hc, Ic, H, 0);
    gemm_bf16<0, 0><<<dim3(H / 128, M / 128), 256, 0, stream>>>(
        Hc, Ic, W2t + i0, I, b2, out, H, Ic, c > 0);
  }
}